// Round 16
// baseline (190.731 us; speedup 1.0000x reference)
//
#include <hip/hip_runtime.h>
#include <hip/hip_bf16.h>

// Problem: B=2, C=64, H=W=96 -> M=N=9216
//   scores[b,m,n] = sum_c yi[b,c,m]*pi[b,c,n] ; weight = softmax over m
//   out[b,c,n]    = sum_m yi[b,c,m]*weight[b,m,n]
// == flash attention with Q=pi (queries n), K=V=yi (keys m), head dim 64.
//
// R16: occupancy has been register-capped at 3 waves/SIMD since R9 (~144
// unified > 128 = 4-wave threshold). Diet to <=128 then pin with
// __launch_bounds__(256,4):
//  (1) half-tile QK: s-half0 -> exp2 -> pack X[0], then half1 (peak s 32->16)
//  (2) ld1 deleted: both dbuf halves are +8192B from buf0 -> one select
//  (3) gstep wave-uniform scalar (waves 0-1 stage kt, 2-3 stage vt)
// P values bit-identical; only run_l f32 add order shifts (~1e-7 drift).
// R4 lesson respected: diet FIRST, then bound (gap closed structurally).
// Spill tripwire: FETCH_SIZE must stay ~21MB; jump -> revert bound next.
// Rest byte-identical to R15 (verified): S=8 split-K, 32x32x16 MFMA,
// 2-product split-bf16 QK, raw-2^s softmax, permlane32_swap PV exchange,
// XCD-locality remap, dbuf one-barrier/tile, hoisted staging pointers.

#define CC 64
#define MM 9216
#define BB 2
#define WAVES 4
#define NPW 32                 // query columns per wave
#define NBLK (WAVES * NPW)     // 128
#define NBX (MM / NBLK)        // 72
#define MTILE 64
#define NT (MM / MTILE)        // 144

typedef __bf16 bf16x8 __attribute__((ext_vector_type(8)));
typedef float f32x16 __attribute__((ext_vector_type(16)));
typedef unsigned int u32x4 __attribute__((ext_vector_type(4)));

// row-XOR swizzle on 8-element groups (verified R2-R15)
__device__ __forceinline__ int swz(int r) { return ((r >> 1) ^ (r >> 4)) & 7; }

__device__ __forceinline__ void gld16(const void* gsrc, void* ldst) {
    __builtin_amdgcn_global_load_lds(
        (const __attribute__((address_space(1))) void*)gsrc,
        (__attribute__((address_space(3))) void*)ldst, 16, 0, 0);
}

// native 2^x
__device__ __forceinline__ float fexp2(float x) {
#if __has_builtin(__builtin_amdgcn_exp2f)
    return __builtin_amdgcn_exp2f(x);
#else
    return exp2f(x);
#endif
}

// pack two f32 -> dword of two bf16
__device__ __forceinline__ unsigned int pack2(float a, float b) {
    const unsigned short ua = __builtin_bit_cast(unsigned short, (__bf16)a);
    const unsigned short ub = __builtin_bit_cast(unsigned short, (__bf16)b);
    return (unsigned int)ua | ((unsigned int)ub << 16);
}

// ---------------- prepass: bake conversion + transpose + swizzle ----------------
// kt[b][m][c ^ (swz(m&63)<<3)]  (m-major: one 8KB contiguous block/tile)
// vt[b][c][t*64 + ((m&63) ^ (swz(c)<<3))]
// grid (NT*2, BB): blockIdx.x&1 selects task half (2.25 blocks/CU)
__global__ __launch_bounds__(256)
void prepass(const float* __restrict__ yi, __bf16* __restrict__ kt,
             __bf16* __restrict__ vt)
{
    const int t    = blockIdx.x >> 1;   // key tile 0..143
    const int half = blockIdx.x & 1;
    const int b    = blockIdx.y;
    const int tsk  = half * 256 + threadIdx.x;   // 0..511
    const float* src = yi + (size_t)b * CC * MM;

    {   // kt task
        const int m = tsk & 63, g = tsk >> 6;
        const int m_abs = t * 64 + m;
        bf16x8 hh;
        #pragma unroll
        for (int j = 0; j < 8; ++j)
            hh[j] = (__bf16)src[(size_t)(g * 8 + j) * MM + m_abs];
        *reinterpret_cast<bf16x8*>(
            kt + (size_t)(b * MM + m_abs) * 64 + ((g ^ swz(m)) << 3)) = hh;
    }
    {   // vt task
        const int c = tsk & 63, gm = tsk >> 6;
        const float* p = src + (size_t)c * MM + t * 64 + gm * 8;
        bf16x8 hh;
        #pragma unroll
        for (int j = 0; j < 8; ++j) hh[j] = (__bf16)p[j];
        *reinterpret_cast<bf16x8*>(
            vt + (size_t)(b * CC + c) * MM + t * 64 + ((gm ^ swz(c)) << 3)) = hh;
    }
}

// ---------------- main flash kernel (32x32x16, raw-2^s softmax, no max) ----------
template<bool FINAL>
__global__ __launch_bounds__(WAVES * 64, 4)   // 4 waves/EU: 128-reg unified cap
void attn_main(const __bf16* __restrict__ kt, const __bf16* __restrict__ vt,
               const float* __restrict__ pi,
               float* __restrict__ out, float* __restrict__ opart,
               float* __restrict__ lpart, const int nsplits)
{
    __shared__ __align__(16) __bf16 k_sm[2][MTILE][64];   // 2 x 8KB
    __shared__ __align__(16) __bf16 v_sm[2][CC][64];      // 2 x 8KB -> 32KB total

    const int tid  = threadIdx.x;
    const int lane = tid & 63;
    const int wave = tid >> 6;     // 0..3
    const int l31  = lane & 31;
    const int hi   = lane >> 5;    // 0/1

    // ---- block decode: XCD-locality map for 1D launches, else plain 3D ----
    int bx, split, b;
    if (gridDim.y == 1 && !FINAL) {
        const int bid = blockIdx.x;              // 0 .. 2*S*NBX-1
        const int xcd = bid & 7, slot = bid >> 3;
        bx = slot % NBX;
        const int g = xcd + 8 * (slot / NBX);    // group 0..2S-1, one XCD each
        split = g % nsplits;
        b     = g / nsplits;
    } else {
        bx = blockIdx.x; split = blockIdx.y; b = blockIdx.z;
    }

    const int tpb = NT / nsplits;
    const int t0s = split * tpb;
    const int n0  = bx * NBLK + wave * NPW;
    const int n_g = n0 + l31;

    // ---- staging state hoisted; chunk type is wave-uniform (0-1: kt, 2-3: vt) ----
    const bool iskt = (wave < 2);
    const int  gstep = iskt ? (MTILE * 64) : MTILE;   // elements per tile
    const __bf16* gq[4];
    char* ld0[4];
    #pragma unroll
    for (int q = 0; q < 4; ++q) {
        const int ch = wave * 4 + q;             // wave-uniform
        if (iskt) {
            gq[q]  = kt + (size_t)(b * MM + t0s * 64) * 64 + ch * 512 + lane * 8;
            ld0[q] = (char*)(&k_sm[0][0][0]) + ch * 1024;
        } else {
            const int j = ch - 8;
            const int c = j * 8 + (lane >> 3);
            gq[q]  = vt + (size_t)(b * CC + c) * MM + t0s * 64 + (lane & 7) * 8;
            ld0[q] = (char*)(&v_sm[0][0][0]) + j * 1024;
        }
    }
    auto stage = [&](int bb) {   // buf1 dest = buf0 dest + 8192B (both arrays)
        const int off = bb ? 8192 : 0;
        #pragma unroll
        for (int q = 0; q < 4; ++q) {
            gld16(gq[q], ld0[q] + off);
            gq[q] += gstep;
        }
    };

    stage(0);   // tile t0s in flight while Q loads below

    // ---- Q fragments (hi/lo split), log2e folded in: s = log2e * (q.k) ----
    const float LOG2E = 1.4426950408889634f;
    bf16x8 qh[4], ql[4];
    {
        const float* qb = pi + (size_t)b * CC * MM + n_g;
        #pragma unroll
        for (int ks = 0; ks < 4; ++ks)
            #pragma unroll
            for (int j = 0; j < 8; ++j) {
                const float f = qb[(size_t)(ks * 16 + hi * 8 + j) * MM] * LOG2E;
                const __bf16 h = (__bf16)f;
                qh[ks][j] = h;
                ql[ks][j] = (__bf16)(f - (float)h);
            }
    }

    f32x16 o0, o1;
    #pragma unroll
    for (int r = 0; r < 16; ++r) { o0[r] = 0.f; o1[r] = 0.f; }
    float run_l = 0.f;

    const int sx0 = swz(l31) << 3;        // row swizzle, rows 0..31
    const int sx1 = swz(32 + l31) << 3;   // rows 32..63

    __syncthreads();   // vmcnt drained -> buf0 ready
    int buf = 0;

    for (int it = 0; it < tpb; ++it) {
        // ---- prefetch next tile into the other buffer; drains under compute ----
        if (it + 1 < tpb) stage(buf ^ 1);

        // ---- QK^T + softmax numerators, one 32-row half at a time ----
        // (halves peak s-register liveness: 32 -> 16 regs)
        unsigned int X[2][4][2];
        float psum = 0.f;
        #pragma unroll
        for (int h = 0; h < 2; ++h) {
            const int sxh = h ? sx1 : sx0;
            const int row = h * 32 + l31;
            f32x16 s;
            #pragma unroll
            for (int r = 0; r < 16; ++r) s[r] = 0.f;
            __builtin_amdgcn_s_setprio(1);
            #pragma unroll
            for (int ks = 0; ks < 4; ++ks) {
                const int cb = ks * 16 + hi * 8;
                const bf16x8 a = *(const bf16x8*)&k_sm[buf][row][cb ^ sxh];
                s = __builtin_amdgcn_mfma_f32_32x32x16_bf16(a, qh[ks], s, 0, 0, 0);
                s = __builtin_amdgcn_mfma_f32_32x32x16_bf16(a, ql[ks], s, 0, 0, 0);
            }
            __builtin_amdgcn_s_setprio(0);

            float ps[8];
            #pragma unroll
            for (int r = 0; r < 8; ++r) {
                s[r]     = fexp2(s[r]);          // P = 2^s, no max (R12 bound proof)
                s[r + 8] = fexp2(s[r + 8]);
                ps[r] = s[r] + s[r + 8];
            }
            psum += ((ps[0] + ps[1]) + (ps[2] + ps[3])) +
                    ((ps[4] + ps[5]) + (ps[6] + ps[7]));
            #pragma unroll
            for (int q = 0; q < 4; ++q)
                #pragma unroll
                for (int d = 0; d < 2; ++d)
                    X[h][q][d] = pack2(s[4 * q + 2 * d], s[4 * q + 2 * d + 1]);
        }
        psum += __shfl_xor(psum, 32);            // R6-verified reduce
        run_l += psum;

        // ---- PV: B-frag via permlane32_swap (R14-verified mapping) ----
        __builtin_amdgcn_s_setprio(1);
        #pragma unroll
        for (int ks = 0; ks < 4; ++ks) {
            const int mt = ks >> 1, e = ks & 1;
            auto rA = __builtin_amdgcn_permlane32_swap(
                X[mt][2 * e][0], X[mt][2 * e + 1][0], false, false);
            auto rB = __builtin_amdgcn_permlane32_swap(
                X[mt][2 * e][1], X[mt][2 * e + 1][1], false, false);
            u32x4 w;
            w.x = rA[0];   // j=0..1
            w.y = rB[0];   // j=2..3
            w.z = rA[1];   // j=4..5
            w.w = rB[1];   // j=6..7
            const bf16x8 bp = __builtin_bit_cast(bf16x8, w);

            const int cb = ks * 16 + hi * 8;
            const bf16x8 av0 = *(const bf16x8*)&v_sm[buf][l31][cb ^ sx0];
            const bf16x8 av1 = *(const bf16x8*)&v_sm[buf][32 + l31][cb ^ sx1];
            o0 = __builtin_amdgcn_mfma_f32_32x32x16_bf16(av0, bp, o0, 0, 0, 0);
            o1 = __builtin_amdgcn_mfma_f32_32x32x16_bf16(av1, bp, o1, 0, 0, 0);
        }
        __builtin_amdgcn_s_setprio(0);

        // ONE barrier: all waves done reading buf (it can be overwritten next
        // iter) AND the pre-barrier vmcnt drain publishes buf^1 for next iter.
        __syncthreads();
        buf ^= 1;
    }

    // ---- epilogue: c = (r&3) + 8*(r>>2) + 4*hi ----
    if (FINAL) {
        const float inv = 1.f / run_l;
        #pragma unroll
        for (int r = 0; r < 16; ++r) {
            const int cl = (r & 3) + 8 * (r >> 2) + 4 * hi;
            out[((size_t)b * CC + cl) * MM + n_g]      = o0[r] * inv;
            out[((size_t)b * CC + cl + 32) * MM + n_g] = o1[r] * inv;
        }
    } else {
        const size_t pbase = (size_t)(b * nsplits + split) * CC * MM;
        #pragma unroll
        for (int r = 0; r < 16; ++r) {
            const int cl = (r & 3) + 8 * (r >> 2) + 4 * hi;
            opart[pbase + (size_t)cl * MM + n_g]        = o0[r];
            opart[pbase + (size_t)(cl + 32) * MM + n_g] = o1[r];
        }
        if (hi == 0)   // lanes n and n+32 hold identical run_l
            lpart[(size_t)(b * nsplits + split) * MM + n_g] = run_l;
    }
}

// out = sum_s O_s / sum_s l_s  -- pure sums, no exp/max (shared zero baseline)
template<int S>
__global__ __launch_bounds__(256)
void attn_reduce4(const float* __restrict__ opart, const float* __restrict__ lpart,
                  float* __restrict__ out)
{
    const int t = blockIdx.x * 256 + threadIdx.x;
    if (t >= BB * CC * MM / 4) return;
    const int n  = (t * 4) % MM;
    const int bc = (t * 4) / MM;
    const int b  = bc / CC;
    const int c  = bc - b * CC;

    float L[4]   = {0.f, 0.f, 0.f, 0.f};
    float acc[4] = {0.f, 0.f, 0.f, 0.f};
    #pragma unroll
    for (int s = 0; s < S; ++s) {
        const float4 l4 = *reinterpret_cast<const float4*>(
            &lpart[(size_t)(b * S + s) * MM + n]);
        L[0] += l4.x; L[1] += l4.y; L[2] += l4.z; L[3] += l4.w;
        const float4 o4 = *reinterpret_cast<const float4*>(
            &opart[((size_t)(b * S + s) * CC + c) * MM + n]);
        acc[0] += o4.x; acc[1] += o4.y; acc[2] += o4.z; acc[3] += o4.w;
    }
    float4 r;
    r.x = acc[0] / L[0]; r.y = acc[1] / L[1];
    r.z = acc[2] / L[2]; r.w = acc[3] / L[3];
    *reinterpret_cast<float4*>(&out[(size_t)t * 4]) = r;
}

extern "C" void kernel_launch(void* const* d_in, const int* in_sizes, int n_in,
                              void* d_out, int out_size, void* d_ws, size_t ws_size,
                              hipStream_t stream) {
    const float* yi = (const float*)d_in[0];   // feature_yi (K = V)
    const float* pi = (const float*)d_in[1];   // feature_pi (Q)
    float* out = (float*)d_out;

    const size_t kelems = (size_t)BB * MM * 64;              // kt elements
    const size_t velems = (size_t)BB * CC * MM;              // vt elements
    const size_t preB   = (kelems + velems) * 2;             // ~4.7 MB
    auto need = [&](int s) -> size_t {
        return preB + (size_t)BB * s * CC * MM * 4 + (size_t)BB * s * MM * 4;
    };

    int S = 1;
    if (d_ws) {
        if (ws_size >= need(8))      S = 8;   // best total (R12/R13 A/B)
        else if (ws_size >= need(4)) S = 4;
        else if (ws_size >= need(2)) S = 2;
    }

    if (S == 1) {
        if (!d_ws || ws_size < preB) return;
        __bf16* kt = (__bf16*)d_ws;
        __bf16* vt = kt + kelems;
        prepass<<<dim3(NT * 2, BB), dim3(256), 0, stream>>>(yi, kt, vt);
        attn_main<true><<<dim3(NBX, 1, BB), dim3(WAVES * 64), 0, stream>>>(
            kt, vt, pi, out, out, out, 1);
        return;
    }

    __bf16* kt   = (__bf16*)d_ws;
    __bf16* vt   = kt + kelems;
    float* opart = (float*)(vt + velems);
    float* lp    = opart + (size_t)BB * S * CC * MM;

    prepass<<<dim3(NT * 2, BB), dim3(256), 0, stream>>>(yi, kt, vt);

    if (S == 8) {
        // 1D grid, XCD-locality mapping: all NBX n-blocks of a (b,split)
        // group land on one XCD (g = xcd + 8*(slot/NBX); bijective).
        attn_main<false><<<dim3(NBX * 2 * S), dim3(WAVES * 64), 0, stream>>>(
            kt, vt, pi, out, opart, lp, S);
    } else {
        attn_main<false><<<dim3(NBX, S, BB), dim3(WAVES * 64), 0, stream>>>(
            kt, vt, pi, out, opart, lp, S);
    }

    const int total4 = BB * CC * MM / 4;
    const dim3 rg((total4 + 255) / 256), rb(256);
    if (S == 8)      attn_reduce4<8><<<rg, rb, 0, stream>>>(opart, lp, out);
    else if (S == 4) attn_reduce4<4><<<rg, rb, 0, stream>>>(opart, lp, out);
    else             attn_reduce4<2><<<rg, rb, 0, stream>>>(opart, lp, out);
}

// Round 17
// 91.384 us; speedup vs baseline: 2.0871x; 2.0871x over previous
//
#include <hip/hip_runtime.h>
#include <hip/hip_bf16.h>

// Problem: B=2, C=64, H=W=96 -> M=N=9216
//   scores[b,m,n] = sum_c yi[b,c,m]*pi[b,c,n] ; weight = softmax over m
//   out[b,c,n]    = sum_m yi[b,c,m]*weight[b,m,n]
// == flash attention with Q=pi (queries n), K=V=yi (keys m), head dim 64.
//
// R17: R16's forced __launch_bounds__(256,4) spilled (VGPR capped at 64,
// FETCH_SIZE 21->120MB = scratch traffic, dur 190us) -- true unified need
// ~144 regs; 128 can't hold it. Measured twice (R4, R16): 3 waves/SIMD is
// the spill-free floor. Bound reverted to 2; the R16 register diet is KEPT
// (half-tile QK, ld1 deletion, scalar gstep -- arithmetic-preserving,
// absmax bit-identical through the spill). Compiler now allocates freely:
// worst case = R15 (91.4us), best case the diet buys a natural 4th wave.
// Rest byte-identical to R15/R16 (verified): S=8 split-K, 32x32x16 MFMA,
// 2-product split-bf16 QK, raw-2^s softmax (score bound 92 log2-units
// << f32 range), permlane32_swap PV exchange, XCD-locality remap,
// dbuf one-barrier/tile, hoisted staging pointers.

#define CC 64
#define MM 9216
#define BB 2
#define WAVES 4
#define NPW 32                 // query columns per wave
#define NBLK (WAVES * NPW)     // 128
#define NBX (MM / NBLK)        // 72
#define MTILE 64
#define NT (MM / MTILE)        // 144

typedef __bf16 bf16x8 __attribute__((ext_vector_type(8)));
typedef float f32x16 __attribute__((ext_vector_type(16)));
typedef unsigned int u32x4 __attribute__((ext_vector_type(4)));

// row-XOR swizzle on 8-element groups (verified R2-R16)
__device__ __forceinline__ int swz(int r) { return ((r >> 1) ^ (r >> 4)) & 7; }

__device__ __forceinline__ void gld16(const void* gsrc, void* ldst) {
    __builtin_amdgcn_global_load_lds(
        (const __attribute__((address_space(1))) void*)gsrc,
        (__attribute__((address_space(3))) void*)ldst, 16, 0, 0);
}

// native 2^x
__device__ __forceinline__ float fexp2(float x) {
#if __has_builtin(__builtin_amdgcn_exp2f)
    return __builtin_amdgcn_exp2f(x);
#else
    return exp2f(x);
#endif
}

// pack two f32 -> dword of two bf16
__device__ __forceinline__ unsigned int pack2(float a, float b) {
    const unsigned short ua = __builtin_bit_cast(unsigned short, (__bf16)a);
    const unsigned short ub = __builtin_bit_cast(unsigned short, (__bf16)b);
    return (unsigned int)ua | ((unsigned int)ub << 16);
}

// ---------------- prepass: bake conversion + transpose + swizzle ----------------
// kt[b][m][c ^ (swz(m&63)<<3)]  (m-major: one 8KB contiguous block/tile)
// vt[b][c][t*64 + ((m&63) ^ (swz(c)<<3))]
// grid (NT*2, BB): blockIdx.x&1 selects task half (2.25 blocks/CU)
__global__ __launch_bounds__(256)
void prepass(const float* __restrict__ yi, __bf16* __restrict__ kt,
             __bf16* __restrict__ vt)
{
    const int t    = blockIdx.x >> 1;   // key tile 0..143
    const int half = blockIdx.x & 1;
    const int b    = blockIdx.y;
    const int tsk  = half * 256 + threadIdx.x;   // 0..511
    const float* src = yi + (size_t)b * CC * MM;

    {   // kt task
        const int m = tsk & 63, g = tsk >> 6;
        const int m_abs = t * 64 + m;
        bf16x8 hh;
        #pragma unroll
        for (int j = 0; j < 8; ++j)
            hh[j] = (__bf16)src[(size_t)(g * 8 + j) * MM + m_abs];
        *reinterpret_cast<bf16x8*>(
            kt + (size_t)(b * MM + m_abs) * 64 + ((g ^ swz(m)) << 3)) = hh;
    }
    {   // vt task
        const int c = tsk & 63, gm = tsk >> 6;
        const float* p = src + (size_t)c * MM + t * 64 + gm * 8;
        bf16x8 hh;
        #pragma unroll
        for (int j = 0; j < 8; ++j) hh[j] = (__bf16)p[j];
        *reinterpret_cast<bf16x8*>(
            vt + (size_t)(b * CC + c) * MM + t * 64 + ((gm ^ swz(c)) << 3)) = hh;
    }
}

// ---------------- main flash kernel (32x32x16, raw-2^s softmax, no max) ----------
template<bool FINAL>
__global__ __launch_bounds__(WAVES * 64, 2)   // NO forced 4-wave cap (R4/R16 lesson)
void attn_main(const __bf16* __restrict__ kt, const __bf16* __restrict__ vt,
               const float* __restrict__ pi,
               float* __restrict__ out, float* __restrict__ opart,
               float* __restrict__ lpart, const int nsplits)
{
    __shared__ __align__(16) __bf16 k_sm[2][MTILE][64];   // 2 x 8KB
    __shared__ __align__(16) __bf16 v_sm[2][CC][64];      // 2 x 8KB -> 32KB total

    const int tid  = threadIdx.x;
    const int lane = tid & 63;
    const int wave = tid >> 6;     // 0..3
    const int l31  = lane & 31;
    const int hi   = lane >> 5;    // 0/1

    // ---- block decode: XCD-locality map for 1D launches, else plain 3D ----
    int bx, split, b;
    if (gridDim.y == 1 && !FINAL) {
        const int bid = blockIdx.x;              // 0 .. 2*S*NBX-1
        const int xcd = bid & 7, slot = bid >> 3;
        bx = slot % NBX;
        const int g = xcd + 8 * (slot / NBX);    // group 0..2S-1, one XCD each
        split = g % nsplits;
        b     = g / nsplits;
    } else {
        bx = blockIdx.x; split = blockIdx.y; b = blockIdx.z;
    }

    const int tpb = NT / nsplits;
    const int t0s = split * tpb;
    const int n0  = bx * NBLK + wave * NPW;
    const int n_g = n0 + l31;

    // ---- staging state hoisted; chunk type is wave-uniform (0-1: kt, 2-3: vt) ----
    const bool iskt = (wave < 2);
    const int  gstep = iskt ? (MTILE * 64) : MTILE;   // elements per tile
    const __bf16* gq[4];
    char* ld0[4];
    #pragma unroll
    for (int q = 0; q < 4; ++q) {
        const int ch = wave * 4 + q;             // wave-uniform
        if (iskt) {
            gq[q]  = kt + (size_t)(b * MM + t0s * 64) * 64 + ch * 512 + lane * 8;
            ld0[q] = (char*)(&k_sm[0][0][0]) + ch * 1024;
        } else {
            const int j = ch - 8;
            const int c = j * 8 + (lane >> 3);
            gq[q]  = vt + (size_t)(b * CC + c) * MM + t0s * 64 + (lane & 7) * 8;
            ld0[q] = (char*)(&v_sm[0][0][0]) + j * 1024;
        }
    }
    auto stage = [&](int bb) {   // buf1 dest = buf0 dest + 8192B (both arrays)
        const int off = bb ? 8192 : 0;
        #pragma unroll
        for (int q = 0; q < 4; ++q) {
            gld16(gq[q], ld0[q] + off);
            gq[q] += gstep;
        }
    };

    stage(0);   // tile t0s in flight while Q loads below

    // ---- Q fragments (hi/lo split), log2e folded in: s = log2e * (q.k) ----
    const float LOG2E = 1.4426950408889634f;
    bf16x8 qh[4], ql[4];
    {
        const float* qb = pi + (size_t)b * CC * MM + n_g;
        #pragma unroll
        for (int ks = 0; ks < 4; ++ks)
            #pragma unroll
            for (int j = 0; j < 8; ++j) {
                const float f = qb[(size_t)(ks * 16 + hi * 8 + j) * MM] * LOG2E;
                const __bf16 h = (__bf16)f;
                qh[ks][j] = h;
                ql[ks][j] = (__bf16)(f - (float)h);
            }
    }

    f32x16 o0, o1;
    #pragma unroll
    for (int r = 0; r < 16; ++r) { o0[r] = 0.f; o1[r] = 0.f; }
    float run_l = 0.f;

    const int sx0 = swz(l31) << 3;        // row swizzle, rows 0..31
    const int sx1 = swz(32 + l31) << 3;   // rows 32..63

    __syncthreads();   // vmcnt drained -> buf0 ready
    int buf = 0;

    for (int it = 0; it < tpb; ++it) {
        // ---- prefetch next tile into the other buffer; drains under compute ----
        if (it + 1 < tpb) stage(buf ^ 1);

        // ---- QK^T + softmax numerators, one 32-row half at a time ----
        // (halves peak s-register liveness: 32 -> 16 regs)
        unsigned int X[2][4][2];
        float psum = 0.f;
        #pragma unroll
        for (int h = 0; h < 2; ++h) {
            const int sxh = h ? sx1 : sx0;
            const int row = h * 32 + l31;
            f32x16 s;
            #pragma unroll
            for (int r = 0; r < 16; ++r) s[r] = 0.f;
            __builtin_amdgcn_s_setprio(1);
            #pragma unroll
            for (int ks = 0; ks < 4; ++ks) {
                const int cb = ks * 16 + hi * 8;
                const bf16x8 a = *(const bf16x8*)&k_sm[buf][row][cb ^ sxh];
                s = __builtin_amdgcn_mfma_f32_32x32x16_bf16(a, qh[ks], s, 0, 0, 0);
                s = __builtin_amdgcn_mfma_f32_32x32x16_bf16(a, ql[ks], s, 0, 0, 0);
            }
            __builtin_amdgcn_s_setprio(0);

            float ps[8];
            #pragma unroll
            for (int r = 0; r < 8; ++r) {
                s[r]     = fexp2(s[r]);          // P = 2^s, no max (R12 bound proof)
                s[r + 8] = fexp2(s[r + 8]);
                ps[r] = s[r] + s[r + 8];
            }
            psum += ((ps[0] + ps[1]) + (ps[2] + ps[3])) +
                    ((ps[4] + ps[5]) + (ps[6] + ps[7]));
            #pragma unroll
            for (int q = 0; q < 4; ++q)
                #pragma unroll
                for (int d = 0; d < 2; ++d)
                    X[h][q][d] = pack2(s[4 * q + 2 * d], s[4 * q + 2 * d + 1]);
        }
        psum += __shfl_xor(psum, 32);            // R6-verified reduce
        run_l += psum;

        // ---- PV: B-frag via permlane32_swap (R14-verified mapping) ----
        __builtin_amdgcn_s_setprio(1);
        #pragma unroll
        for (int ks = 0; ks < 4; ++ks) {
            const int mt = ks >> 1, e = ks & 1;
            auto rA = __builtin_amdgcn_permlane32_swap(
                X[mt][2 * e][0], X[mt][2 * e + 1][0], false, false);
            auto rB = __builtin_amdgcn_permlane32_swap(
                X[mt][2 * e][1], X[mt][2 * e + 1][1], false, false);
            u32x4 w;
            w.x = rA[0];   // j=0..1
            w.y = rB[0];   // j=2..3
            w.z = rA[1];   // j=4..5
            w.w = rB[1];   // j=6..7
            const bf16x8 bp = __builtin_bit_cast(bf16x8, w);

            const int cb = ks * 16 + hi * 8;
            const bf16x8 av0 = *(const bf16x8*)&v_sm[buf][l31][cb ^ sx0];
            const bf16x8 av1 = *(const bf16x8*)&v_sm[buf][32 + l31][cb ^ sx1];
            o0 = __builtin_amdgcn_mfma_f32_32x32x16_bf16(av0, bp, o0, 0, 0, 0);
            o1 = __builtin_amdgcn_mfma_f32_32x32x16_bf16(av1, bp, o1, 0, 0, 0);
        }
        __builtin_amdgcn_s_setprio(0);

        // ONE barrier: all waves done reading buf (it can be overwritten next
        // iter) AND the pre-barrier vmcnt drain publishes buf^1 for next iter.
        __syncthreads();
        buf ^= 1;
    }

    // ---- epilogue: c = (r&3) + 8*(r>>2) + 4*hi ----
    if (FINAL) {
        const float inv = 1.f / run_l;
        #pragma unroll
        for (int r = 0; r < 16; ++r) {
            const int cl = (r & 3) + 8 * (r >> 2) + 4 * hi;
            out[((size_t)b * CC + cl) * MM + n_g]      = o0[r] * inv;
            out[((size_t)b * CC + cl + 32) * MM + n_g] = o1[r] * inv;
        }
    } else {
        const size_t pbase = (size_t)(b * nsplits + split) * CC * MM;
        #pragma unroll
        for (int r = 0; r < 16; ++r) {
            const int cl = (r & 3) + 8 * (r >> 2) + 4 * hi;
            opart[pbase + (size_t)cl * MM + n_g]        = o0[r];
            opart[pbase + (size_t)(cl + 32) * MM + n_g] = o1[r];
        }
        if (hi == 0)   // lanes n and n+32 hold identical run_l
            lpart[(size_t)(b * nsplits + split) * MM + n_g] = run_l;
    }
}

// out = sum_s O_s / sum_s l_s  -- pure sums, no exp/max (shared zero baseline)
template<int S>
__global__ __launch_bounds__(256)
void attn_reduce4(const float* __restrict__ opart, const float* __restrict__ lpart,
                  float* __restrict__ out)
{
    const int t = blockIdx.x * 256 + threadIdx.x;
    if (t >= BB * CC * MM / 4) return;
    const int n  = (t * 4) % MM;
    const int bc = (t * 4) / MM;
    const int b  = bc / CC;
    const int c  = bc - b * CC;

    float L[4]   = {0.f, 0.f, 0.f, 0.f};
    float acc[4] = {0.f, 0.f, 0.f, 0.f};
    #pragma unroll
    for (int s = 0; s < S; ++s) {
        const float4 l4 = *reinterpret_cast<const float4*>(
            &lpart[(size_t)(b * S + s) * MM + n]);
        L[0] += l4.x; L[1] += l4.y; L[2] += l4.z; L[3] += l4.w;
        const float4 o4 = *reinterpret_cast<const float4*>(
            &opart[((size_t)(b * S + s) * CC + c) * MM + n]);
        acc[0] += o4.x; acc[1] += o4.y; acc[2] += o4.z; acc[3] += o4.w;
    }
    float4 r;
    r.x = acc[0] / L[0]; r.y = acc[1] / L[1];
    r.z = acc[2] / L[2]; r.w = acc[3] / L[3];
    *reinterpret_cast<float4*>(&out[(size_t)t * 4]) = r;
}

extern "C" void kernel_launch(void* const* d_in, const int* in_sizes, int n_in,
                              void* d_out, int out_size, void* d_ws, size_t ws_size,
                              hipStream_t stream) {
    const float* yi = (const float*)d_in[0];   // feature_yi (K = V)
    const float* pi = (const float*)d_in[1];   // feature_pi (Q)
    float* out = (float*)d_out;

    const size_t kelems = (size_t)BB * MM * 64;              // kt elements
    const size_t velems = (size_t)BB * CC * MM;              // vt elements
    const size_t preB   = (kelems + velems) * 2;             // ~4.7 MB
    auto need = [&](int s) -> size_t {
        return preB + (size_t)BB * s * CC * MM * 4 + (size_t)BB * s * MM * 4;
    };

    int S = 1;
    if (d_ws) {
        if (ws_size >= need(8))      S = 8;   // best total (R12/R13 A/B)
        else if (ws_size >= need(4)) S = 4;
        else if (ws_size >= need(2)) S = 2;
    }

    if (S == 1) {
        if (!d_ws || ws_size < preB) return;
        __bf16* kt = (__bf16*)d_ws;
        __bf16* vt = kt + kelems;
        prepass<<<dim3(NT * 2, BB), dim3(256), 0, stream>>>(yi, kt, vt);
        attn_main<true><<<dim3(NBX, 1, BB), dim3(WAVES * 64), 0, stream>>>(
            kt, vt, pi, out, out, out, 1);
        return;
    }

    __bf16* kt   = (__bf16*)d_ws;
    __bf16* vt   = kt + kelems;
    float* opart = (float*)(vt + velems);
    float* lp    = opart + (size_t)BB * S * CC * MM;

    prepass<<<dim3(NT * 2, BB), dim3(256), 0, stream>>>(yi, kt, vt);

    if (S == 8) {
        // 1D grid, XCD-locality mapping: all NBX n-blocks of a (b,split)
        // group land on one XCD (g = xcd + 8*(slot/NBX); bijective).
        attn_main<false><<<dim3(NBX * 2 * S), dim3(WAVES * 64), 0, stream>>>(
            kt, vt, pi, out, opart, lp, S);
    } else {
        attn_main<false><<<dim3(NBX, S, BB), dim3(WAVES * 64), 0, stream>>>(
            kt, vt, pi, out, opart, lp, S);
    }

    const int total4 = BB * CC * MM / 4;
    const dim3 rg((total4 + 255) / 256), rb(256);
    if (S == 8)      attn_reduce4<8><<<rg, rb, 0, stream>>>(opart, lp, out);
    else if (S == 4) attn_reduce4<4><<<rg, rb, 0, stream>>>(opart, lp, out);
    else             attn_reduce4<2><<<rg, rb, 0, stream>>>(opart, lp, out);
}